// Round 19
// baseline (25.517 us; speedup 1.0000x reference)
//
#include <hip/hip_runtime.h>
#include <hip/hip_fp16.h>

typedef float v2 __attribute__((ext_vector_type(2)));

constexpr int NN = 1024;
constexpr int GC = 64;          // cells per side; corner grid 65x65, spacing 1/64
constexpr float GS = 64.0f;
constexpr int NC = GC * GC;     // 4096 cells

__device__ __forceinline__ float fast_tanh(float x) {
    float e = exp2f(x * 2.88539008177792681472f);
    return 1.0f - 2.0f * __builtin_amdgcn_rcpf(1.0f + e);
}

__device__ __forceinline__ v2 mlp_eval(float x, float y,
    const float* __restrict__ W1, const float* __restrict__ b1,
    const float* __restrict__ W2, const float* __restrict__ b2,
    const float* __restrict__ W3, const float* __restrict__ b3)
{
    float h1[10], h2[10];
#pragma unroll
    for (int k = 0; k < 10; ++k)
        h1[k] = fast_tanh(fmaf(x, W1[k], fmaf(y, W1[10 + k], b1[k])));
#pragma unroll
    for (int k = 0; k < 10; ++k) {
        float acc = b2[k];
#pragma unroll
        for (int l = 0; l < 10; ++l) acc = fmaf(h1[l], W2[10 * l + k], acc);
        h2[k] = fast_tanh(acc);
    }
    float f0 = b3[0], f1 = b3[1];
#pragma unroll
    for (int k = 0; k < 10; ++k) {
        f0 = fmaf(h2[k], W3[2 * k], f0);
        f1 = fmaf(h2[k], W3[2 * k + 1], f1);
    }
    v2 r; r.x = f0; r.y = f1;
    return r;
}

__device__ __forceinline__ unsigned pack2h(float lo, float hi) {
    return (unsigned)__half_as_ushort(__float2half(lo))
         | ((unsigned)__half_as_ushort(__float2half(hi)) << 16);
}

__device__ __forceinline__ float2 unpack2h(unsigned u) {
    union { unsigned x; __half2 h; } c; c.x = u;
    return __half22float2(c.h);
}

// ---- kernel A: per-cell plane model packed as 6 x f16; 64 blocks x 64 thr ----
__global__ __launch_bounds__(64) void cells_kernel(
    const float* __restrict__ W1, const float* __restrict__ b1,
    const float* __restrict__ W2, const float* __restrict__ b2,
    const float* __restrict__ W3, const float* __restrict__ b3,
    uint4* __restrict__ g)
{
    const int c = blockIdx.x * 64 + threadIdx.x;
    if (c >= NC) return;
    const int ix = c & (GC - 1), iy = c >> 6;
    const float x0 = (float)ix * (1.0f / GS), x1 = (float)(ix + 1) * (1.0f / GS);
    const float y0 = (float)iy * (1.0f / GS), y1 = (float)(iy + 1) * (1.0f / GS);

    const v2 f00 = mlp_eval(x0, y0, W1, b1, W2, b2, W3, b3);
    const v2 f10 = mlp_eval(x1, y0, W1, b1, W2, b2, W3, b3);
    const v2 f01 = mlp_eval(x0, y1, W1, b1, W2, b2, W3, b3);

    uint4 w;
    w.x = pack2h(f00.x, f00.y);
    w.y = pack2h(f10.x - f00.x, f10.y - f00.y);   // dfx
    w.z = pack2h(f01.x - f00.x, f01.y - f00.y);   // dfy
    w.w = 0;
    g[c] = w;
}

// ---- kernel B: LDS f16 plane table; atomic-free smax-sorted balanced waves ----
__global__ __launch_bounds__(1024, 8) void flow_kernel(
    const float* __restrict__ pts,
    const uint4* __restrict__ g,
    float* __restrict__ out)
{
    __shared__ uint4 tabL[NC];              // 64 KB (pre-staging: sort scratch)
    __shared__ v2 ptsL[NN];                 // 8 KB
    __shared__ unsigned short ordQ[2 * NN]; // 4 KB

    const int t = threadIdx.x;
    const int lane = t & 63, w = t >> 6;    // wave 0..15
    const int i0 = blockIdx.x << 1;

    ptsL[t] = ((const v2*)pts)[t];
    __syncthreads();

    // ---- keys: smax for (q, j=t), q = 0,1 ----
    int key[2];
#pragma unroll
    for (int q = 0; q < 2; ++q) {
        const int i = i0 + q;
        const float ddx = ptsL[t].x - ptsL[i].x;
        const float ddy = ptsL[t].y - ptsL[i].y;
        const float n2 = __fadd_rn(__fmul_rn(ddx, ddx), __fmul_rn(ddy, ddy));
        const float e  = __fsqrt_rn(n2);
        const int  nv  = (int)floorf(__fdiv_rn(e, 0.1f));
        key[q] = (nv < 15) ? nv : 15;
    }

    // ---- ballot histogram: counts per (bucket k, wave w, q) + in-group rank ----
    int* cntA = (int*)tabL;         // 512 ints
    int* cntB = (int*)tabL + 512;   // scan ping-pong
    const unsigned long long lt = (lane == 0) ? 0ull : (~0ull >> (64 - lane));
    int myRank[2];
#pragma unroll
    for (int q = 0; q < 2; ++q) {
#pragma unroll
        for (int k = 0; k < 16; ++k) {
            const unsigned long long m = __ballot(key[q] == k);
            if (key[q] == k) myRank[q] = __popcll(m & lt);
            if (lane == k) cntA[(k << 5) | (w << 1) | q] = __popcll(m);
        }
    }
    __syncthreads();

    // ---- inclusive Hillis-Steele scan over 512 entries (flat (k,w,q)) ----
    int orig = 0;
    if (t < 512) orig = cntA[t];
    int* src = cntA; int* dst = cntB;
    for (int off = 1; off < 512; off <<= 1) {
        if (t < 512) { int x = src[t]; if (t >= off) x += src[t - off]; dst[t] = x; }
        __syncthreads();
        int* tmp = src; src = dst; dst = tmp;
    }
    if (t < 512) dst[t] = src[t] - orig;    // exclusive base
    __syncthreads();

    // ---- deterministic rank scatter ----
#pragma unroll
    for (int q = 0; q < 2; ++q) {
        const int slot = dst[(key[q] << 5) | (w << 1) | q] + myRank[q];
        ordQ[slot] = (unsigned short)((q << 10) | t);
    }
    __syncthreads();

    // ---- stage table (overwrites sort scratch) ----
#pragma unroll
    for (int k = 0; k < 4; ++k)
        tabL[t + 1024 * k] = g[t + 1024 * k];
    __syncthreads();

    // ---- main: 2 rounds; wave w takes sorted slices (w, 31-w) -> balanced ----
#pragma unroll 1
    for (int r = 0; r < 2; ++r) {
        const int sidx = (r == 0) ? w : (31 - w);
        const int item = ordQ[(sidx << 6) | lane];
        const int q = item >> 10, jj = item & (NN - 1);
        const int i = i0 + q;

        const float x1x = ptsL[i].x,  x1y = ptsL[i].y;
        const float x2x = ptsL[jj].x, x2y = ptsL[jj].y;
        const float dx = x2x - x1x, dy = x2y - x1y;

        // Exact non-contracted f32 sequence for the floor() step-count boundary.
        const float nrm2 = __fadd_rn(__fmul_rn(dx, dx), __fmul_rn(dy, dy));
        const float euc  = __fsqrt_rn(nrm2);
        const float se   = (euc > 0.0f) ? euc : 1.0f;
        const float ux   = __fdiv_rn(dx, se), uy = __fdiv_rn(dy, se);
        const int   nvi  = (int)floorf(__fdiv_rn(euc, 0.1f));
        const int   smax = (nvi < 15) ? nvi : 15;

        float pu = x1x * GS, pv = x1y * GS;
        const float du = 6.4f * ux, dv = 6.4f * uy;       // 0.1 * GS
        const float dxe = -1.44269504088896340736f * dx;
        const float dye = -1.44269504088896340736f * dy;

        float cost = 0.0f;
#pragma unroll 2
        for (int s = 0; s <= smax; ++s) {
            int ix = (int)pu; ix = (ix < GC - 1) ? ix : (GC - 1);
            int iy = (int)pv; iy = (iy < GC - 1) ? iy : (GC - 1);
            const float tx = pu - (float)ix;
            const float ty = pv - (float)iy;

            const uint4 cw = tabL[(iy << 6) + ix];        // single ds_read_b128
            const float2 a   = unpack2h(cw.x);
            const float2 gdx = unpack2h(cw.y);
            const float2 gdy = unpack2h(cw.z);
            const float fx = fmaf(ty, gdy.x, fmaf(tx, gdx.x, a.x));
            const float fy = fmaf(ty, gdy.y, fmaf(tx, gdx.y, a.y));

            const float de = fmaf(fx, dxe, fy * dye);     // = -dot*log2e
            cost += fmaf(0.08f, exp2f(de), 0.02f);        // 0.02 + 0.08*exp(-dot)

            pu += du; pv += dv;
        }

        out[(i << 10) | jj] = (euc > 0.0f) ? cost : 0.0f;
    }
}

extern "C" void kernel_launch(void* const* d_in, const int* in_sizes, int n_in,
                              void* d_out, int out_size, void* d_ws, size_t ws_size,
                              hipStream_t stream) {
    const float* pts = (const float*)d_in[0];
    const float* W1  = (const float*)d_in[1];
    const float* b1  = (const float*)d_in[2];
    const float* W2  = (const float*)d_in[3];
    const float* b2  = (const float*)d_in[4];
    const float* W3  = (const float*)d_in[5];
    const float* b3  = (const float*)d_in[6];
    float* out = (float*)d_out;

    uint4* g = (uint4*)d_ws;   // 4096 * 16 = 65536 B of scratch

    cells_kernel<<<NC / 64, 64, 0, stream>>>(W1, b1, W2, b2, W3, b3, g);
    flow_kernel<<<NN / 2, 1024, 0, stream>>>(pts, g, out);
}

// Round 20
// 23.432 us; speedup vs baseline: 1.0890x; 1.0890x over previous
//
#include <hip/hip_runtime.h>
#include <hip/hip_fp16.h>

typedef float v2 __attribute__((ext_vector_type(2)));

constexpr int NN = 1024;
constexpr int GC = 64;          // cells per side; corner grid 65x65, spacing 1/64
constexpr float GS = 64.0f;
constexpr int NC = GC * GC;     // 4096 cells
constexpr int G2 = GC + 1;      // 65 corners per side
constexpr int NCOR = G2 * G2;   // 4225 corners

__device__ __forceinline__ float fast_tanh(float x) {
    float e = exp2f(x * 2.88539008177792681472f);
    return 1.0f - 2.0f * __builtin_amdgcn_rcpf(1.0f + e);
}

__device__ __forceinline__ v2 mlp_eval(float x, float y,
    const float* __restrict__ W1, const float* __restrict__ b1,
    const float* __restrict__ W2, const float* __restrict__ b2,
    const float* __restrict__ W3, const float* __restrict__ b3)
{
    float h1[10], h2[10];
#pragma unroll
    for (int k = 0; k < 10; ++k)
        h1[k] = fast_tanh(fmaf(x, W1[k], fmaf(y, W1[10 + k], b1[k])));
#pragma unroll
    for (int k = 0; k < 10; ++k) {
        float acc = b2[k];
#pragma unroll
        for (int l = 0; l < 10; ++l) acc = fmaf(h1[l], W2[10 * l + k], acc);
        h2[k] = fast_tanh(acc);
    }
    float f0 = b3[0], f1 = b3[1];
#pragma unroll
    for (int k = 0; k < 10; ++k) {
        f0 = fmaf(h2[k], W3[2 * k], f0);
        f1 = fmaf(h2[k], W3[2 * k + 1], f1);
    }
    v2 r; r.x = f0; r.y = f1;
    return r;
}

__device__ __forceinline__ unsigned pack2h(float lo, float hi) {
    return (unsigned)__half_as_ushort(__float2half(lo))
         | ((unsigned)__half_as_ushort(__float2half(hi)) << 16);
}

__device__ __forceinline__ float2 unpack2h(unsigned u) {
    union { unsigned x; __half2 h; } c; c.x = u;
    return __half22float2(c.h);
}

// ---- kernel A: one MLP eval per corner (4225 threads) ----
__global__ __launch_bounds__(256) void corners_kernel(
    const float* __restrict__ W1, const float* __restrict__ b1,
    const float* __restrict__ W2, const float* __restrict__ b2,
    const float* __restrict__ W3, const float* __restrict__ b3,
    v2* __restrict__ cor)
{
    const int c = blockIdx.x * 256 + threadIdx.x;
    if (c >= NCOR) return;
    const int ix = c % G2, iy = c / G2;
    cor[c] = mlp_eval((float)ix * (1.0f / GS), (float)iy * (1.0f / GS),
                      W1, b1, W2, b2, W3, b3);
}

// ---- kernel B: stage+pack plane table into LDS; one ds_read_b128 per step ----
__global__ __launch_bounds__(1024, 8) void flow_kernel(
    const float* __restrict__ pts,
    const v2* __restrict__ cor,
    float* __restrict__ out)
{
    __shared__ uint4 tabL[NC];   // 64 KB -> 2 blocks/CU, 8 waves/SIMD

    const int t = threadIdx.x;
#pragma unroll
    for (int k = 0; k < 4; ++k) {
        const int c = t + 1024 * k;
        const int ix = c & (GC - 1), iy = c >> 6;
        const int i00 = iy * G2 + ix;
        const v2 f00 = cor[i00];
        const v2 f10 = cor[i00 + 1];
        const v2 f01 = cor[i00 + G2];
        uint4 w;
        w.x = pack2h(f00.x, f00.y);
        w.y = pack2h(f10.x - f00.x, f10.y - f00.y);   // dfx
        w.z = pack2h(f01.x - f00.x, f01.y - f00.y);   // dfy
        w.w = 0;
        tabL[c] = w;
    }
    __syncthreads();

    const v2 pj = ((const v2*)pts)[t];    // this thread's target (coalesced)
    const float x2x = pj.x, x2y = pj.y;

#pragma unroll 1
    for (int q = 0; q < 2; ++q) {
        const int i = (blockIdx.x << 1) + q;              // source (uniform)
        const float x1x = pts[2 * i], x1y = pts[2 * i + 1];
        const float dx = x2x - x1x, dy = x2y - x1y;

        // Exact non-contracted f32 sequence for the floor() step-count boundary.
        const float nrm2 = __fadd_rn(__fmul_rn(dx, dx), __fmul_rn(dy, dy));
        const float euc  = __fsqrt_rn(nrm2);
        const float se   = (euc > 0.0f) ? euc : 1.0f;
        const float ux   = __fdiv_rn(dx, se), uy = __fdiv_rn(dy, se);
        const int   nvi  = (int)floorf(__fdiv_rn(euc, 0.1f));
        const int   smax = (nvi < 15) ? nvi : 15;

        float pu = x1x * GS, pv = x1y * GS;
        const float du = 6.4f * ux, dv = 6.4f * uy;       // 0.1 * GS
        const float dxe = -1.44269504088896340736f * dx;
        const float dye = -1.44269504088896340736f * dy;

        float cost = 0.0f;
#pragma unroll 1
        for (int s = 0; s <= smax; ++s) {
            int ix = (int)pu; ix = (ix < GC - 1) ? ix : (GC - 1);
            int iy = (int)pv; iy = (iy < GC - 1) ? iy : (GC - 1);
            const float tx = pu - (float)ix;
            const float ty = pv - (float)iy;

            const uint4 w = tabL[(iy << 6) + ix];         // single ds_read_b128
            const float2 a   = unpack2h(w.x);
            const float2 gdx = unpack2h(w.y);
            const float2 gdy = unpack2h(w.z);
            const float fx = fmaf(ty, gdy.x, fmaf(tx, gdx.x, a.x));
            const float fy = fmaf(ty, gdy.y, fmaf(tx, gdx.y, a.y));

            const float de = fmaf(fx, dxe, fy * dye);     // = -dot*log2e
            cost += fmaf(0.08f, exp2f(de), 0.02f);        // 0.02 + 0.08*exp(-dot)

            pu += du; pv += dv;
        }

        out[(i << 10) | t] = (euc > 0.0f) ? cost : 0.0f;
    }
}

extern "C" void kernel_launch(void* const* d_in, const int* in_sizes, int n_in,
                              void* d_out, int out_size, void* d_ws, size_t ws_size,
                              hipStream_t stream) {
    const float* pts = (const float*)d_in[0];
    const float* W1  = (const float*)d_in[1];
    const float* b1  = (const float*)d_in[2];
    const float* W2  = (const float*)d_in[3];
    const float* b2  = (const float*)d_in[4];
    const float* W3  = (const float*)d_in[5];
    const float* b3  = (const float*)d_in[6];
    float* out = (float*)d_out;

    v2* cor = (v2*)d_ws;   // 4225 * 8 = 33800 B of scratch

    corners_kernel<<<(NCOR + 255) / 256, 256, 0, stream>>>(W1, b1, W2, b2, W3, b3, cor);
    flow_kernel<<<NN / 2, 1024, 0, stream>>>(pts, cor, out);
}

// Round 21
// 22.355 us; speedup vs baseline: 1.1415x; 1.0482x over previous
//
#include <hip/hip_runtime.h>
#include <hip/hip_fp16.h>

typedef float v2 __attribute__((ext_vector_type(2)));

constexpr int NN = 1024;
constexpr int GC = 64;          // cells per side; corner grid 65x65, spacing 1/64
constexpr float GS = 64.0f;
constexpr int NC = GC * GC;     // 4096 cells

__device__ __forceinline__ float fast_tanh(float x) {
    float e = exp2f(x * 2.88539008177792681472f);
    return 1.0f - 2.0f * __builtin_amdgcn_rcpf(1.0f + e);
}

__device__ __forceinline__ v2 mlp_eval(float x, float y,
    const float* __restrict__ W1, const float* __restrict__ b1,
    const float* __restrict__ W2, const float* __restrict__ b2,
    const float* __restrict__ W3, const float* __restrict__ b3)
{
    float h1[10], h2[10];
#pragma unroll
    for (int k = 0; k < 10; ++k)
        h1[k] = fast_tanh(fmaf(x, W1[k], fmaf(y, W1[10 + k], b1[k])));
#pragma unroll
    for (int k = 0; k < 10; ++k) {
        float acc = b2[k];
#pragma unroll
        for (int l = 0; l < 10; ++l) acc = fmaf(h1[l], W2[10 * l + k], acc);
        h2[k] = fast_tanh(acc);
    }
    float f0 = b3[0], f1 = b3[1];
#pragma unroll
    for (int k = 0; k < 10; ++k) {
        f0 = fmaf(h2[k], W3[2 * k], f0);
        f1 = fmaf(h2[k], W3[2 * k + 1], f1);
    }
    v2 r; r.x = f0; r.y = f1;
    return r;
}

__device__ __forceinline__ unsigned pack2h(float lo, float hi) {
    return (unsigned)__half_as_ushort(__float2half(lo))
         | ((unsigned)__half_as_ushort(__float2half(hi)) << 16);
}

__device__ __forceinline__ float2 unpack2h(unsigned u) {
    union { unsigned x; __half2 h; } c; c.x = u;
    return __half22float2(c.h);
}

// ---- kernel A: per-cell plane model packed as 6 x f16 in one 16B slot ----
__global__ __launch_bounds__(256) void cells_kernel(
    const float* __restrict__ W1, const float* __restrict__ b1,
    const float* __restrict__ W2, const float* __restrict__ b2,
    const float* __restrict__ W3, const float* __restrict__ b3,
    uint4* __restrict__ g)
{
    const int c = blockIdx.x * 256 + threadIdx.x;
    if (c >= NC) return;
    const int ix = c & (GC - 1), iy = c >> 6;
    const float x0 = (float)ix * (1.0f / GS), x1 = (float)(ix + 1) * (1.0f / GS);
    const float y0 = (float)iy * (1.0f / GS), y1 = (float)(iy + 1) * (1.0f / GS);

    const v2 f00 = mlp_eval(x0, y0, W1, b1, W2, b2, W3, b3);
    const v2 f10 = mlp_eval(x1, y0, W1, b1, W2, b2, W3, b3);
    const v2 f01 = mlp_eval(x0, y1, W1, b1, W2, b2, W3, b3);

    uint4 w;
    w.x = pack2h(f00.x, f00.y);
    w.y = pack2h(f10.x - f00.x, f10.y - f00.y);   // dfx
    w.z = pack2h(f01.x - f00.x, f01.y - f00.y);   // dfy
    w.w = 0;
    g[c] = w;
}

// ---- kernel B: LDS f16 plane table, one ds_read_b128 per step; 2 sources/block ----
__global__ __launch_bounds__(1024, 8) void flow_kernel(
    const float* __restrict__ pts,
    const uint4* __restrict__ g,
    float* __restrict__ out)
{
    __shared__ uint4 tabL[NC];   // 64 KB -> 2 blocks/CU, 8 waves/SIMD

    const int t = threadIdx.x;
#pragma unroll
    for (int k = 0; k < 4; ++k)
        tabL[t + 1024 * k] = g[t + 1024 * k];
    __syncthreads();

    const v2 pj = ((const v2*)pts)[t];    // this thread's target (coalesced)
    const float x2x = pj.x, x2y = pj.y;

#pragma unroll 1
    for (int q = 0; q < 2; ++q) {
        const int i = (blockIdx.x << 1) + q;              // source (uniform)
        const float x1x = pts[2 * i], x1y = pts[2 * i + 1];
        const float dx = x2x - x1x, dy = x2y - x1y;

        // Exact non-contracted f32 sequence for the floor() step-count boundary.
        const float nrm2 = __fadd_rn(__fmul_rn(dx, dx), __fmul_rn(dy, dy));
        const float euc  = __fsqrt_rn(nrm2);
        const float se   = (euc > 0.0f) ? euc : 1.0f;
        const float ux   = __fdiv_rn(dx, se), uy = __fdiv_rn(dy, se);
        const int   nvi  = (int)floorf(__fdiv_rn(euc, 0.1f));
        const int   smax = (nvi < 15) ? nvi : 15;

        float pu = x1x * GS, pv = x1y * GS;
        const float du = 6.4f * ux, dv = 6.4f * uy;       // 0.1 * GS
        const float dxe = -1.44269504088896340736f * dx;
        const float dye = -1.44269504088896340736f * dy;

        float cost = 0.0f;
#pragma unroll 1
        for (int s = 0; s <= smax; ++s) {
            int ix = (int)pu; ix = (ix < GC - 1) ? ix : (GC - 1);
            int iy = (int)pv; iy = (iy < GC - 1) ? iy : (GC - 1);
            const float tx = pu - (float)ix;
            const float ty = pv - (float)iy;

            const uint4 w = tabL[(iy << 6) + ix];         // single ds_read_b128
            const float2 a   = unpack2h(w.x);
            const float2 gdx = unpack2h(w.y);
            const float2 gdy = unpack2h(w.z);
            const float fx = fmaf(ty, gdy.x, fmaf(tx, gdx.x, a.x));
            const float fy = fmaf(ty, gdy.y, fmaf(tx, gdx.y, a.y));

            const float de = fmaf(fx, dxe, fy * dye);     // = -dot*log2e
            cost += fmaf(0.08f, exp2f(de), 0.02f);        // 0.02 + 0.08*exp(-dot)

            pu += du; pv += dv;
        }

        out[(i << 10) | t] = (euc > 0.0f) ? cost : 0.0f;
    }
}

extern "C" void kernel_launch(void* const* d_in, const int* in_sizes, int n_in,
                              void* d_out, int out_size, void* d_ws, size_t ws_size,
                              hipStream_t stream) {
    const float* pts = (const float*)d_in[0];
    const float* W1  = (const float*)d_in[1];
    const float* b1  = (const float*)d_in[2];
    const float* W2  = (const float*)d_in[3];
    const float* b2  = (const float*)d_in[4];
    const float* W3  = (const float*)d_in[5];
    const float* b3  = (const float*)d_in[6];
    float* out = (float*)d_out;

    uint4* g = (uint4*)d_ws;   // 4096 * 16 = 65536 B of scratch

    cells_kernel<<<NC / 256, 256, 0, stream>>>(W1, b1, W2, b2, W3, b3, g);
    flow_kernel<<<NN / 2, 1024, 0, stream>>>(pts, g, out);
}